// Round 16
// baseline (125.110 us; speedup 1.0000x reference)
//
#include <hip/hip_runtime.h>
#include <stdint.h>

#define C_DIM 512
#define H_HEADS 8
#define D_HEAD 64
#define B_BATCH 4
#define L_SEQ 2048
#define GROUPS 32
#define EPS_GN 1e-5f

typedef unsigned short u16;
typedef __attribute__((ext_vector_type(8))) __bf16 bf16x8;
typedef __attribute__((ext_vector_type(2))) float f32x2;
typedef __attribute__((ext_vector_type(4))) float f32x4;
typedef __attribute__((ext_vector_type(16))) float f32x16;

__device__ __forceinline__ u16 f2bf(float f) {
  unsigned u = __builtin_bit_cast(unsigned, f);
  unsigned r = u + 0x7FFFu + ((u >> 16) & 1u);
  return (u16)(r >> 16);
}

__device__ __forceinline__ float bf2f(u16 h) {
  unsigned u = ((unsigned)h) << 16;
  return __builtin_bit_cast(float, u);
}

__device__ __forceinline__ unsigned cvtpk_bf16(float lo, float hi) {
  unsigned r;
  asm("v_cvt_pk_bf16_f32 %0, %1, %2" : "=v"(r) : "v"(lo), "v"(hi));
  return r;
}

__device__ __forceinline__ void pl32swap(unsigned& a, unsigned& b) {
  asm("v_permlane32_swap_b32 %0, %1" : "+v"(a), "+v"(b));
}

__device__ __forceinline__ bf16x8 mk8(unsigned a, unsigned b, unsigned c, unsigned d) {
  union { uint4 u; bf16x8 v; } z;
  z.u.x = a; z.u.y = b; z.u.z = c; z.u.w = d;
  return z.v;
}

// global -> LDS direct (16B per lane; dest = wave-uniform base + lane*16)
__device__ __forceinline__ void gl16(const void* g, void* l) {
  __builtin_amdgcn_global_load_lds((const __attribute__((address_space(1))) void*)g,
                                   (__attribute__((address_space(3))) void*)l, 16, 0, 0);
}

// ------------------------------------------------- prep: groupnorm + weights
__global__ __launch_bounds__(256) void prep_kernel(const float* __restrict__ x,
                                                   const float* __restrict__ gamma,
                                                   const float* __restrict__ beta,
                                                   const float* __restrict__ wq,
                                                   const float* __restrict__ wp,
                                                   u16* __restrict__ h_t,
                                                   u16* __restrict__ wq_bf,
                                                   u16* __restrict__ wp_bf) {
  if (blockIdx.x >= 128) {
    int i = (blockIdx.x - 128) * 256 + threadIdx.x;
    const int nq = 3 * C_DIM * C_DIM;
    int idx = i * 4;
    const float* src;
    u16* dst;
    if (idx < nq) { src = wq + idx; dst = wq_bf + idx; }
    else          { src = wp + (idx - nq); dst = wp_bf + (idx - nq); }
    float4 v = *(const float4*)src;
    uint2 pk;
    pk.x = cvtpk_bf16(v.x, v.y);
    pk.y = cvtpk_bf16(v.z, v.w);
    *(uint2*)dst = pk;
    return;
  }
  int bg = blockIdx.x;
  int b = bg >> 5, g = bg & 31;
  const float* base = x + ((size_t)(b * C_DIM + g * 16)) * L_SEQ;
  int t = threadIdx.x;
  int w = t >> 6;
  float s = 0.f, sq = 0.f;
  for (int i = 0; i < 32; ++i) {
    float4 v = ((const float4*)base)[t + i * 256];
    s += v.x + v.y + v.z + v.w;
    sq += v.x * v.x + v.y * v.y + v.z * v.z + v.w * v.w;
  }
  for (int off = 32; off; off >>= 1) { s += __shfl_down(s, off); sq += __shfl_down(sq, off); }
  __shared__ float red[8];
  if ((t & 63) == 0) { red[w * 2] = s; red[w * 2 + 1] = sq; }
  __syncthreads();
  float ts = red[0] + red[2] + red[4] + red[6];
  float tq = red[1] + red[3] + red[5] + red[7];
  float mean = ts * (1.f / 32768.f);
  float var = tq * (1.f / 32768.f) - mean * mean;
  float rstd = rsqrtf(var + EPS_GN);
  float ga[16], be[16];
#pragma unroll
  for (int c = 0; c < 16; ++c) {
    float gm = gamma[g * 16 + c];
    ga[c] = gm * rstd;
    be[c] = beta[g * 16 + c] - mean * gm * rstd;
  }
  __shared__ float tile[16][260];
  for (int lc = 0; lc < 8; ++lc) {
    __syncthreads();
#pragma unroll
    for (int it = 0; it < 4; ++it) {
      int r = it * 4 + w;
      int c4 = (t & 63) * 4;
      *(float4*)&tile[r][c4] = *(const float4*)(base + (size_t)r * L_SEQ + lc * 256 + c4);
    }
    __syncthreads();
    int l = lc * 256 + t;
    unsigned wds[8];
#pragma unroll
    for (int c = 0; c < 8; ++c) {
      float a0 = tile[2 * c][t] * ga[2 * c] + be[2 * c];
      float a1 = tile[2 * c + 1][t] * ga[2 * c + 1] + be[2 * c + 1];
      wds[c] = cvtpk_bf16(a0, a1);
    }
    u16* dst = h_t + ((size_t)(b * L_SEQ + l)) * C_DIM + g * 16;
    uint4 p0; p0.x = wds[0]; p0.y = wds[1]; p0.z = wds[2]; p0.w = wds[3];
    uint4 p1; p1.x = wds[4]; p1.y = wds[5]; p1.z = wds[6]; p1.w = wds[7];
    *(uint4*)dst = p0;
    *(uint4*)(dst + 8) = p1;
  }
}

// ---------------------------------------------------------------- QKV GEMM
// (round-3 proven form) 128x128 tile, global_load_lds, rotate-swizzle LDS.
__global__ __launch_bounds__(256) void gemm_qkv(const u16* __restrict__ A_bf,
                                                const u16* __restrict__ B_t,
                                                const float* __restrict__ bias,
                                                u16* __restrict__ q_t,
                                                u16* __restrict__ kf_g,
                                                u16* __restrict__ vf_g) {
  constexpr int K = 512;
  __shared__ u16 A_lds[128][32];
  __shared__ u16 B_lds[128][32];
  int t = threadIdx.x;
  int w = t >> 6, lane = t & 63;
  int q4 = lane >> 4, c15 = lane & 15;
  int wm = w >> 1, wn = w & 1;
  int o0 = blockIdx.y * 128;
  int l0 = blockIdx.x * 128;
  int b = blockIdx.z;
  const u16* Bb = B_t + (size_t)b * L_SEQ * K;
  f32x4 acc[4][4] = {};

  int sr = lane >> 2, sc = lane & 3;
  int r0 = w * 32 + sr;
  int r1 = r0 + 16;
  int lc0 = (sc - (r0 >> 1)) & 3;
  int lc1 = (sc - (r1 >> 1)) & 3;
  const u16* Ag0 = A_bf + (size_t)(o0 + r0) * K + lc0 * 8;
  const u16* Ag1 = A_bf + (size_t)(o0 + r1) * K + lc1 * 8;
  const u16* Bg0 = Bb + (size_t)(l0 + r0) * K + lc0 * 8;
  const u16* Bg1 = Bb + (size_t)(l0 + r1) * K + lc1 * 8;
  u16* Al0 = &A_lds[w * 32][0];
  u16* Al1 = &A_lds[w * 32 + 16][0];
  u16* Bl0 = &B_lds[w * 32][0];
  u16* Bl1 = &B_lds[w * 32 + 16][0];

  for (int kt = 0; kt < K / 32; ++kt) {
    gl16(Ag0, Al0); gl16(Ag1, Al1);
    gl16(Bg0, Bl0); gl16(Bg1, Bl1);
    Ag0 += 32; Ag1 += 32; Bg0 += 32; Bg1 += 32;
    __syncthreads();
    bf16x8 af[4], bfr[4];
#pragma unroll
    for (int mi = 0; mi < 4; ++mi) {
      int ar = wm * 64 + mi * 16 + c15;
      af[mi] = *(const bf16x8*)&A_lds[ar][((q4 + (ar >> 1)) & 3) * 8];
    }
#pragma unroll
    for (int ni = 0; ni < 4; ++ni) {
      int br = wn * 64 + ni * 16 + c15;
      bfr[ni] = *(const bf16x8*)&B_lds[br][((q4 + (br >> 1)) & 3) * 8];
    }
#pragma unroll
    for (int mi = 0; mi < 4; ++mi)
#pragma unroll
      for (int ni = 0; ni < 4; ++ni)
        acc[mi][ni] = __builtin_amdgcn_mfma_f32_16x16x32_bf16(af[mi], bfr[ni], acc[mi][ni], 0, 0, 0);
    __syncthreads();
  }

  const float QS = 0.18033688f;  // 0.125 * log2(e) folded into Q
  int sel = o0 >> 9;
  int ob = o0 - sel * 512 + wm * 64;
#pragma unroll
  for (int mi = 0; mi < 4; ++mi) {
    int orow = ob + mi * 16 + q4 * 4;
    float4 bi = *(const float4*)&bias[o0 + wm * 64 + mi * 16 + q4 * 4];
#pragma unroll
    for (int ni = 0; ni < 4; ++ni) {
      int l = l0 + wn * 64 + ni * 16 + c15;
      float v0 = acc[mi][ni][0] + bi.x;
      float v1 = acc[mi][ni][1] + bi.y;
      float v2 = acc[mi][ni][2] + bi.z;
      float v3 = acc[mi][ni][3] + bi.w;
      if (sel == 0) {
        v0 *= QS; v1 *= QS; v2 *= QS; v3 *= QS;
        uint2 pk;
        pk.x = cvtpk_bf16(v0, v1);
        pk.y = cvtpk_bf16(v2, v3);
        *(uint2*)(q_t + ((size_t)(b * L_SEQ + l)) * C_DIM + orow) = pk;
      } else if (sel == 1) {
        // K fragment: KF[bh][(kv>>5)*4 + d>>4][(kv&31)+32*((d>>3)&1)][d&7]
        int hh = orow >> 6, d = orow & 63;
        size_t base = ((size_t)(b * 8 + hh)) * 131072 +
                      (size_t)(((l >> 5) * 4 + (d >> 4))) * 512 +
                      (size_t)((l & 31) + ((d >> 3) & 1) * 32) * 8 + (d & 7);
        uint2 pk;
        pk.x = cvtpk_bf16(v0, v1);
        pk.y = cvtpk_bf16(v2, v3);
        *(uint2*)(kf_g + base) = pk;
      } else {
        // V fragment: VF[bh][(kv>>4)*2 + d>>5][(d&31)+32*((kv>>3)&1)][kv&7]
        int hh = orow >> 6, d = orow & 63;
        size_t base0 = ((size_t)(b * 8 + hh)) * 131072 +
                       (size_t)(l >> 4) * 1024 +
                       (size_t)((l >> 3) & 1) * 256 + (l & 7);
        vf_g[base0 + (size_t)((d + 0) >> 5) * 512 + ((d + 0) & 31) * 8] = f2bf(v0);
        vf_g[base0 + (size_t)((d + 1) >> 5) * 512 + ((d + 1) & 31) * 8] = f2bf(v1);
        vf_g[base0 + (size_t)((d + 2) >> 5) * 512 + ((d + 2) & 31) * 8] = f2bf(v2);
        vf_g[base0 + (size_t)((d + 3) >> 5) * 512 + ((d + 3) & 31) * 8] = f2bf(v3);
      }
    }
  }
}

// ---------------------------------------------------------------- proj GEMM
// 64(M) x 128(L) tile -> 512 blocks (2/CU) for HBM-write overlap.
__global__ __launch_bounds__(256) void gemm_proj(const u16* __restrict__ A_bf,
                                                 const u16* __restrict__ B_t,
                                                 const float* __restrict__ bias,
                                                 const float* __restrict__ xres,
                                                 float* __restrict__ out_f) {
  constexpr int K = 512;
  __shared__ u16 A_lds[64][32];
  __shared__ u16 B_lds[128][32];
  int t = threadIdx.x;
  int w = t >> 6, lane = t & 63;
  int q4 = lane >> 4, c15 = lane & 15;
  int o0 = blockIdx.y * 64;
  int l0 = blockIdx.x * 128;
  int b = blockIdx.z;
  const u16* Bb = B_t + (size_t)b * L_SEQ * K;
  f32x4 acc[4][2] = {};

  int sr = lane >> 2, sc = lane & 3;
  int ra = w * 16 + sr;
  int lca = (sc - (ra >> 1)) & 3;
  const u16* Ag = A_bf + (size_t)(o0 + ra) * K + lca * 8;
  int rb0 = w * 32 + sr, rb1 = rb0 + 16;
  int lcb0 = (sc - (rb0 >> 1)) & 3;
  int lcb1 = (sc - (rb1 >> 1)) & 3;
  const u16* Bg0 = Bb + (size_t)(l0 + rb0) * K + lcb0 * 8;
  const u16* Bg1 = Bb + (size_t)(l0 + rb1) * K + lcb1 * 8;
  u16* Al = &A_lds[w * 16][0];
  u16* Bl0 = &B_lds[w * 32][0];
  u16* Bl1 = &B_lds[w * 32 + 16][0];

  for (int kt = 0; kt < K / 32; ++kt) {
    gl16(Ag, Al);
    gl16(Bg0, Bl0); gl16(Bg1, Bl1);
    Ag += 32; Bg0 += 32; Bg1 += 32;
    __syncthreads();
    bf16x8 af[4], bfr[2];
#pragma unroll
    for (int mi = 0; mi < 4; ++mi) {
      int ar = mi * 16 + c15;
      af[mi] = *(const bf16x8*)&A_lds[ar][((q4 + (ar >> 1)) & 3) * 8];
    }
#pragma unroll
    for (int ni = 0; ni < 2; ++ni) {
      int br = w * 32 + ni * 16 + c15;
      bfr[ni] = *(const bf16x8*)&B_lds[br][((q4 + (br >> 1)) & 3) * 8];
    }
#pragma unroll
    for (int mi = 0; mi < 4; ++mi)
#pragma unroll
      for (int ni = 0; ni < 2; ++ni)
        acc[mi][ni] = __builtin_amdgcn_mfma_f32_16x16x32_bf16(af[mi], bfr[ni], acc[mi][ni], 0, 0, 0);
    __syncthreads();
  }

#pragma unroll
  for (int mi = 0; mi < 4; ++mi) {
    int orow = o0 + mi * 16 + q4 * 4;
    float4 bi = *(const float4*)&bias[orow];
#pragma unroll
    for (int ni = 0; ni < 2; ++ni) {
      int l = l0 + w * 32 + ni * 16 + c15;
      size_t base2 = ((size_t)(b * C_DIM + orow)) * L_SEQ + l;
      out_f[base2] = acc[mi][ni][0] + bi.x + xres[base2];
      out_f[base2 + L_SEQ] = acc[mi][ni][1] + bi.y + xres[base2 + L_SEQ];
      out_f[base2 + 2 * L_SEQ] = acc[mi][ni][2] + bi.z + xres[base2 + 2 * L_SEQ];
      out_f[base2 + 3 * L_SEQ] = acc[mi][ni][3] + bi.w + xres[base2 + 3 * L_SEQ];
    }
  }
}

// ---------------------------------------------------------------- attention
// (round-15 structure) + bf16 merge buffer: LDS 33.3KB -> 17.4KB so the
// LDS residency cap rises 4 -> 9 blocks/CU (VGPR allows ~6). NO-MAX softmax,
// S-pipeline, K+V register double-buffers. 2-way LDS merge in bf16.
#define ABODY(KL, KN, VC, SC, SN, T)                                           \
  {                                                                            \
    int tl = (T) + 2; tl = tl > 31 ? 31 : tl;                                  \
    const u16* kp = kfb + tl * 2048;                                           \
    const u16* vp = vfb + tl * 2048;                                           \
    KL[0] = *(const bf16x8*)(kp);                                              \
    KL[1] = *(const bf16x8*)(kp + 512);                                        \
    KL[2] = *(const bf16x8*)(kp + 1024);                                       \
    KL[3] = *(const bf16x8*)(kp + 1536);                                       \
    _Pragma("unroll") for (int r = 0; r < 16; ++r) SN[r] = 0.f;                \
    SN = __builtin_amdgcn_mfma_f32_32x32x16_bf16(KN[0], qf[0], SN, 0, 0, 0);   \
    SN = __builtin_amdgcn_mfma_f32_32x32x16_bf16(KN[1], qf[1], SN, 0, 0, 0);   \
    SN = __builtin_amdgcn_mfma_f32_32x32x16_bf16(KN[2], qf[2], SN, 0, 0, 0);   \
    SN = __builtin_amdgcn_mfma_f32_32x32x16_bf16(KN[3], qf[3], SN, 0, 0, 0);   \
    float e[16];                                                               \
    _Pragma("unroll") for (int r = 0; r < 16; ++r)                             \
        e[r] = __builtin_amdgcn_exp2f(SC[r]);                                  \
    f32x2 a0_ = {e[0], e[1]}, a1_ = {e[2], e[3]}, a2_ = {e[4], e[5]},          \
          a3_ = {e[6], e[7]}, a4_ = {e[8], e[9]}, a5_ = {e[10], e[11]},        \
          a6_ = {e[12], e[13]}, a7_ = {e[14], e[15]};                          \
    f32x2 b0_ = a0_ + a1_, b1_ = a2_ + a3_, b2_ = a4_ + a5_, b3_ = a6_ + a7_;  \
    f32x2 c0_ = b0_ + b1_, c1_ = b2_ + b3_;                                    \
    f32x2 d0_ = c0_ + c1_;                                                     \
    float sum = d0_[0] + d0_[1];                                               \
    sum += __shfl_xor(sum, 32);                                                \
    l_r += sum;                                                                \
    unsigned pk[8];                                                            \
    _Pragma("unroll") for (int i = 0; i < 8; ++i)                              \
        pk[i] = cvtpk_bf16(e[2 * i], e[2 * i + 1]);                            \
    pl32swap(pk[0], pk[2]); pl32swap(pk[1], pk[3]);                            \
    pl32swap(pk[4], pk[6]); pl32swap(pk[5], pk[7]);                            \
    bf16x8 pf0 = mk8(pk[0], pk[1], pk[2], pk[3]);                              \
    bf16x8 pf1 = mk8(pk[4], pk[5], pk[6], pk[7]);                              \
    o0 = __builtin_amdgcn_mfma_f32_32x32x16_bf16(VC[0], pf0, o0, 0, 0, 0);     \
    o1 = __builtin_amdgcn_mfma_f32_32x32x16_bf16(VC[1], pf0, o1, 0, 0, 0);     \
    o0 = __builtin_amdgcn_mfma_f32_32x32x16_bf16(VC[2], pf1, o0, 0, 0, 0);     \
    o1 = __builtin_amdgcn_mfma_f32_32x32x16_bf16(VC[3], pf1, o1, 0, 0, 0);     \
    VC[0] = *(const bf16x8*)(vp);                                              \
    VC[1] = *(const bf16x8*)(vp + 512);                                        \
    VC[2] = *(const bf16x8*)(vp + 1024);                                       \
    VC[3] = *(const bf16x8*)(vp + 1536);                                       \
  }

#define AEPI(VC, SC)                                                           \
  {                                                                            \
    float e[16];                                                               \
    _Pragma("unroll") for (int r = 0; r < 16; ++r)                             \
        e[r] = __builtin_amdgcn_exp2f(SC[r]);                                  \
    f32x2 a0_ = {e[0], e[1]}, a1_ = {e[2], e[3]}, a2_ = {e[4], e[5]},          \
          a3_ = {e[6], e[7]}, a4_ = {e[8], e[9]}, a5_ = {e[10], e[11]},        \
          a6_ = {e[12], e[13]}, a7_ = {e[14], e[15]};                          \
    f32x2 b0_ = a0_ + a1_, b1_ = a2_ + a3_, b2_ = a4_ + a5_, b3_ = a6_ + a7_;  \
    f32x2 c0_ = b0_ + b1_, c1_ = b2_ + b3_;                                    \
    f32x2 d0_ = c0_ + c1_;                                                     \
    float sum = d0_[0] + d0_[1];                                               \
    sum += __shfl_xor(sum, 32);                                                \
    l_r += sum;                                                                \
    unsigned pk[8];                                                            \
    _Pragma("unroll") for (int i = 0; i < 8; ++i)                              \
        pk[i] = cvtpk_bf16(e[2 * i], e[2 * i + 1]);                            \
    pl32swap(pk[0], pk[2]); pl32swap(pk[1], pk[3]);                            \
    pl32swap(pk[4], pk[6]); pl32swap(pk[5], pk[7]);                            \
    bf16x8 pf0 = mk8(pk[0], pk[1], pk[2], pk[3]);                              \
    bf16x8 pf1 = mk8(pk[4], pk[5], pk[6], pk[7]);                              \
    o0 = __builtin_amdgcn_mfma_f32_32x32x16_bf16(VC[0], pf0, o0, 0, 0, 0);     \
    o1 = __builtin_amdgcn_mfma_f32_32x32x16_bf16(VC[1], pf0, o1, 0, 0, 0);     \
    o0 = __builtin_amdgcn_mfma_f32_32x32x16_bf16(VC[2], pf1, o0, 0, 0, 0);     \
    o1 = __builtin_amdgcn_mfma_f32_32x32x16_bf16(VC[3], pf1, o1, 0, 0, 0);     \
  }

__global__ __launch_bounds__(256, 4) void attn_kernel(const u16* __restrict__ q_t,
                                                      const u16* __restrict__ kf_g,
                                                      const u16* __restrict__ vf_g,
                                                      u16* __restrict__ ao_t) {
  __shared__ u16 oLb[4][64][32];   // bf16 partials (16KB)
  __shared__ float lL[4][32];

  int g = blockIdx.x;
  int wk = (g & 7) * 128 + (g >> 3);  // XCD swizzle: 1024 wgs, 8 XCDs
  int qg = wk & 31, bh = wk >> 5;
  int b = bh >> 3, h = bh & 7;
  int t = threadIdx.x;
  int wv = t >> 6, lane = t & 63;
  int q = lane & 31, hi = lane >> 5;
  int qh = wv & 1, kvh = wv >> 1;
  int q0 = qg * 64 + qh * 32;

  const u16* qp = q_t + ((size_t)(b * L_SEQ + q0 + q)) * C_DIM + h * 64 + hi * 8;
  bf16x8 qf[4];
#pragma unroll
  for (int kk = 0; kk < 4; ++kk) qf[kk] = *(const bf16x8*)(qp + kk * 16);

  // wave's KV half: tiles [kvh*32, kvh*32+32)
  const u16* kfb = kf_g + (size_t)bh * 131072 + (size_t)kvh * 65536 + lane * 8;
  const u16* vfb = vf_g + (size_t)bh * 131072 + (size_t)kvh * 65536 + lane * 8;

  f32x16 o0, o1;
#pragma unroll
  for (int r = 0; r < 16; ++r) { o0[r] = 0.f; o1[r] = 0.f; }
  float l_r = 0.f;

  bf16x8 kA[4], kB[4], vA[4], vB[4];
#pragma unroll
  for (int i = 0; i < 4; ++i) {
    kB[i] = *(const bf16x8*)(kfb + i * 512);           // K(0)
    kA[i] = *(const bf16x8*)(kfb + 2048 + i * 512);    // K(1)
    vA[i] = *(const bf16x8*)(vfb + i * 512);           // V(0)
    vB[i] = *(const bf16x8*)(vfb + 2048 + i * 512);    // V(1)
  }
  f32x16 sA, sB;
#pragma unroll
  for (int r = 0; r < 16; ++r) sA[r] = 0.f;
#pragma unroll
  for (int kk = 0; kk < 4; ++kk)
    sA = __builtin_amdgcn_mfma_f32_32x32x16_bf16(kB[kk], qf[kk], sA, 0, 0, 0);  // S(0)

  for (int it = 0; it < 15; ++it) {
    ABODY(kB, kA, vA, sA, sB, 2 * it);
    ABODY(kA, kB, vB, sB, sA, 2 * it + 1);
  }
  ABODY(kB, kA, vA, sA, sB, 30);
  AEPI(vB, sB);

  // ---- merge 2 KV-halves per q-group via LDS (bf16 partials) ----
  if (hi == 0) lL[wv][q] = l_r;
#pragma unroll
  for (int r = 0; r < 16; ++r) {
    int d = (r & 3) + 8 * (r >> 2) + 4 * hi;
    oLb[wv][d][q] = f2bf(o0[r]);
    oLb[wv][d + 32][q] = f2bf(o1[r]);
  }
  __syncthreads();

  int tq = t & 31;
  int oqh = (t >> 5) & 1;
  int d0 = (t >> 6) * 16;
  float lsum = lL[oqh][tq] + lL[oqh + 2][tq];
  float inv = 1.f / lsum;
  float v[16];
#pragma unroll
  for (int i = 0; i < 16; ++i)
    v[i] = (bf2f(oLb[oqh][d0 + i][tq]) + bf2f(oLb[oqh + 2][d0 + i][tq])) * inv;
  u16* dst = ao_t + ((size_t)(b * L_SEQ + qg * 64 + oqh * 32 + tq)) * C_DIM + h * 64 + d0;
  uint4 ov0, ov1;
  ov0.x = cvtpk_bf16(v[0], v[1]);
  ov0.y = cvtpk_bf16(v[2], v[3]);
  ov0.z = cvtpk_bf16(v[4], v[5]);
  ov0.w = cvtpk_bf16(v[6], v[7]);
  ov1.x = cvtpk_bf16(v[8], v[9]);
  ov1.y = cvtpk_bf16(v[10], v[11]);
  ov1.z = cvtpk_bf16(v[12], v[13]);
  ov1.w = cvtpk_bf16(v[14], v[15]);
  *(uint4*)dst = ov0;
  *(uint4*)(dst + 8) = ov1;
}

// ---------------------------------------------------------------- launch
extern "C" void kernel_launch(void* const* d_in, const int* in_sizes, int n_in,
                              void* d_out, int out_size, void* d_ws, size_t ws_size,
                              hipStream_t stream) {
  const float* x = (const float*)d_in[0];
  const float* gamma = (const float*)d_in[1];
  const float* beta = (const float*)d_in[2];
  const float* w_qkv = (const float*)d_in[3];
  const float* b_qkv = (const float*)d_in[4];
  const float* w_proj = (const float*)d_in[5];
  const float* b_proj = (const float*)d_in[6];
  float* out = (float*)d_out;

  u16* wq_bf = (u16*)d_ws;                 // 786432
  u16* wp_bf = wq_bf + 786432;             // 262144
  u16* h_t = wp_bf + 262144;               // 4194304 (b,l,c)
  u16* q_t = h_t + 4194304;                // (b,l,c), pre-scaled
  u16* kf_g = q_t + 4194304;               // K fragments
  u16* vf_g = kf_g + 4194304;              // V fragments
  u16* ao_t = vf_g + 4194304;              // (b,l,c)

  prep_kernel<<<dim3(1152), dim3(256), 0, stream>>>(x, gamma, beta, w_qkv, w_proj,
                                                    h_t, wq_bf, wp_bf);
  gemm_qkv<<<dim3(16, 12, 4), dim3(256), 0, stream>>>(wq_bf, h_t, b_qkv, q_t, kf_g, vf_g);
  attn_kernel<<<dim3(1024), dim3(256), 0, stream>>>(q_t, kf_g, vf_g, ao_t);
  gemm_proj<<<dim3(16, 8, 4), dim3(256), 0, stream>>>(wp_bf, ao_t, b_proj, x, out);
}

// Round 17
// 98.710 us; speedup vs baseline: 1.2674x; 1.2674x over previous
//
#include <hip/hip_runtime.h>
#include <stdint.h>

#define C_DIM 512
#define H_HEADS 8
#define D_HEAD 64
#define B_BATCH 4
#define L_SEQ 2048
#define GROUPS 32
#define EPS_GN 1e-5f

typedef unsigned short u16;
typedef __attribute__((ext_vector_type(8))) __bf16 bf16x8;
typedef __attribute__((ext_vector_type(2))) float f32x2;
typedef __attribute__((ext_vector_type(4))) float f32x4;
typedef __attribute__((ext_vector_type(16))) float f32x16;

__device__ __forceinline__ u16 f2bf(float f) {
  unsigned u = __builtin_bit_cast(unsigned, f);
  unsigned r = u + 0x7FFFu + ((u >> 16) & 1u);
  return (u16)(r >> 16);
}

__device__ __forceinline__ unsigned cvtpk_bf16(float lo, float hi) {
  unsigned r;
  asm("v_cvt_pk_bf16_f32 %0, %1, %2" : "=v"(r) : "v"(lo), "v"(hi));
  return r;
}

__device__ __forceinline__ void pl32swap(unsigned& a, unsigned& b) {
  asm("v_permlane32_swap_b32 %0, %1" : "+v"(a), "+v"(b));
}

__device__ __forceinline__ bf16x8 mk8(unsigned a, unsigned b, unsigned c, unsigned d) {
  union { uint4 u; bf16x8 v; } z;
  z.u.x = a; z.u.y = b; z.u.z = c; z.u.w = d;
  return z.v;
}

// global -> LDS direct (16B per lane; dest = wave-uniform base + lane*16)
__device__ __forceinline__ void gl16(const void* g, void* l) {
  __builtin_amdgcn_global_load_lds((const __attribute__((address_space(1))) void*)g,
                                   (__attribute__((address_space(3))) void*)l, 16, 0, 0);
}

// ------------------------------------------------- prep: groupnorm + weights
__global__ __launch_bounds__(256) void prep_kernel(const float* __restrict__ x,
                                                   const float* __restrict__ gamma,
                                                   const float* __restrict__ beta,
                                                   const float* __restrict__ wq,
                                                   const float* __restrict__ wp,
                                                   u16* __restrict__ h_t,
                                                   u16* __restrict__ wq_bf,
                                                   u16* __restrict__ wp_bf) {
  if (blockIdx.x >= 128) {
    int i = (blockIdx.x - 128) * 256 + threadIdx.x;
    const int nq = 3 * C_DIM * C_DIM;
    int idx = i * 4;
    const float* src;
    u16* dst;
    if (idx < nq) { src = wq + idx; dst = wq_bf + idx; }
    else          { src = wp + (idx - nq); dst = wp_bf + (idx - nq); }
    float4 v = *(const float4*)src;
    uint2 pk;
    pk.x = cvtpk_bf16(v.x, v.y);
    pk.y = cvtpk_bf16(v.z, v.w);
    *(uint2*)dst = pk;
    return;
  }
  int bg = blockIdx.x;
  int b = bg >> 5, g = bg & 31;
  const float* base = x + ((size_t)(b * C_DIM + g * 16)) * L_SEQ;
  int t = threadIdx.x;
  int w = t >> 6;
  float s = 0.f, sq = 0.f;
  for (int i = 0; i < 32; ++i) {
    float4 v = ((const float4*)base)[t + i * 256];
    s += v.x + v.y + v.z + v.w;
    sq += v.x * v.x + v.y * v.y + v.z * v.z + v.w * v.w;
  }
  for (int off = 32; off; off >>= 1) { s += __shfl_down(s, off); sq += __shfl_down(sq, off); }
  __shared__ float red[8];
  if ((t & 63) == 0) { red[w * 2] = s; red[w * 2 + 1] = sq; }
  __syncthreads();
  float ts = red[0] + red[2] + red[4] + red[6];
  float tq = red[1] + red[3] + red[5] + red[7];
  float mean = ts * (1.f / 32768.f);
  float var = tq * (1.f / 32768.f) - mean * mean;
  float rstd = rsqrtf(var + EPS_GN);
  float ga[16], be[16];
#pragma unroll
  for (int c = 0; c < 16; ++c) {
    float gm = gamma[g * 16 + c];
    ga[c] = gm * rstd;
    be[c] = beta[g * 16 + c] - mean * gm * rstd;
  }
  __shared__ float tile[16][260];
  for (int lc = 0; lc < 8; ++lc) {
    __syncthreads();
#pragma unroll
    for (int it = 0; it < 4; ++it) {
      int r = it * 4 + w;
      int c4 = (t & 63) * 4;
      *(float4*)&tile[r][c4] = *(const float4*)(base + (size_t)r * L_SEQ + lc * 256 + c4);
    }
    __syncthreads();
    int l = lc * 256 + t;
    unsigned wds[8];
#pragma unroll
    for (int c = 0; c < 8; ++c) {
      float a0 = tile[2 * c][t] * ga[2 * c] + be[2 * c];
      float a1 = tile[2 * c + 1][t] * ga[2 * c + 1] + be[2 * c + 1];
      wds[c] = cvtpk_bf16(a0, a1);
    }
    u16* dst = h_t + ((size_t)(b * L_SEQ + l)) * C_DIM + g * 16;
    uint4 p0; p0.x = wds[0]; p0.y = wds[1]; p0.z = wds[2]; p0.w = wds[3];
    uint4 p1; p1.x = wds[4]; p1.y = wds[5]; p1.z = wds[6]; p1.w = wds[7];
    *(uint4*)dst = p0;
    *(uint4*)(dst + 8) = p1;
  }
}

// ---------------------------------------------------------------- QKV GEMM
// (round-3 proven form) 128x128 tile, global_load_lds, rotate-swizzle LDS.
__global__ __launch_bounds__(256) void gemm_qkv(const u16* __restrict__ A_bf,
                                                const u16* __restrict__ B_t,
                                                const float* __restrict__ bias,
                                                u16* __restrict__ q_t,
                                                u16* __restrict__ kf_g,
                                                u16* __restrict__ vf_g) {
  constexpr int K = 512;
  __shared__ u16 A_lds[128][32];
  __shared__ u16 B_lds[128][32];
  int t = threadIdx.x;
  int w = t >> 6, lane = t & 63;
  int q4 = lane >> 4, c15 = lane & 15;
  int wm = w >> 1, wn = w & 1;
  int o0 = blockIdx.y * 128;
  int l0 = blockIdx.x * 128;
  int b = blockIdx.z;
  const u16* Bb = B_t + (size_t)b * L_SEQ * K;
  f32x4 acc[4][4] = {};

  int sr = lane >> 2, sc = lane & 3;
  int r0 = w * 32 + sr;
  int r1 = r0 + 16;
  int lc0 = (sc - (r0 >> 1)) & 3;
  int lc1 = (sc - (r1 >> 1)) & 3;
  const u16* Ag0 = A_bf + (size_t)(o0 + r0) * K + lc0 * 8;
  const u16* Ag1 = A_bf + (size_t)(o0 + r1) * K + lc1 * 8;
  const u16* Bg0 = Bb + (size_t)(l0 + r0) * K + lc0 * 8;
  const u16* Bg1 = Bb + (size_t)(l0 + r1) * K + lc1 * 8;
  u16* Al0 = &A_lds[w * 32][0];
  u16* Al1 = &A_lds[w * 32 + 16][0];
  u16* Bl0 = &B_lds[w * 32][0];
  u16* Bl1 = &B_lds[w * 32 + 16][0];

  for (int kt = 0; kt < K / 32; ++kt) {
    gl16(Ag0, Al0); gl16(Ag1, Al1);
    gl16(Bg0, Bl0); gl16(Bg1, Bl1);
    Ag0 += 32; Ag1 += 32; Bg0 += 32; Bg1 += 32;
    __syncthreads();
    bf16x8 af[4], bfr[4];
#pragma unroll
    for (int mi = 0; mi < 4; ++mi) {
      int ar = wm * 64 + mi * 16 + c15;
      af[mi] = *(const bf16x8*)&A_lds[ar][((q4 + (ar >> 1)) & 3) * 8];
    }
#pragma unroll
    for (int ni = 0; ni < 4; ++ni) {
      int br = wn * 64 + ni * 16 + c15;
      bfr[ni] = *(const bf16x8*)&B_lds[br][((q4 + (br >> 1)) & 3) * 8];
    }
#pragma unroll
    for (int mi = 0; mi < 4; ++mi)
#pragma unroll
      for (int ni = 0; ni < 4; ++ni)
        acc[mi][ni] = __builtin_amdgcn_mfma_f32_16x16x32_bf16(af[mi], bfr[ni], acc[mi][ni], 0, 0, 0);
    __syncthreads();
  }

  const float QS = 0.18033688f;  // 0.125 * log2(e) folded into Q
  int sel = o0 >> 9;
  int ob = o0 - sel * 512 + wm * 64;
#pragma unroll
  for (int mi = 0; mi < 4; ++mi) {
    int orow = ob + mi * 16 + q4 * 4;
    float4 bi = *(const float4*)&bias[o0 + wm * 64 + mi * 16 + q4 * 4];
#pragma unroll
    for (int ni = 0; ni < 4; ++ni) {
      int l = l0 + wn * 64 + ni * 16 + c15;
      float v0 = acc[mi][ni][0] + bi.x;
      float v1 = acc[mi][ni][1] + bi.y;
      float v2 = acc[mi][ni][2] + bi.z;
      float v3 = acc[mi][ni][3] + bi.w;
      if (sel == 0) {
        v0 *= QS; v1 *= QS; v2 *= QS; v3 *= QS;
        uint2 pk;
        pk.x = cvtpk_bf16(v0, v1);
        pk.y = cvtpk_bf16(v2, v3);
        *(uint2*)(q_t + ((size_t)(b * L_SEQ + l)) * C_DIM + orow) = pk;
      } else if (sel == 1) {
        // K fragment: KF[bh][(kv>>5)*4 + d>>4][(kv&31)+32*((d>>3)&1)][d&7]
        int hh = orow >> 6, d = orow & 63;
        size_t base = ((size_t)(b * 8 + hh)) * 131072 +
                      (size_t)(((l >> 5) * 4 + (d >> 4))) * 512 +
                      (size_t)((l & 31) + ((d >> 3) & 1) * 32) * 8 + (d & 7);
        uint2 pk;
        pk.x = cvtpk_bf16(v0, v1);
        pk.y = cvtpk_bf16(v2, v3);
        *(uint2*)(kf_g + base) = pk;
      } else {
        // V fragment: VF[bh][(kv>>4)*2 + d>>5][(d&31)+32*((kv>>3)&1)][kv&7]
        int hh = orow >> 6, d = orow & 63;
        size_t base0 = ((size_t)(b * 8 + hh)) * 131072 +
                       (size_t)(l >> 4) * 1024 +
                       (size_t)((l >> 3) & 1) * 256 + (l & 7);
        vf_g[base0 + (size_t)((d + 0) >> 5) * 512 + ((d + 0) & 31) * 8] = f2bf(v0);
        vf_g[base0 + (size_t)((d + 1) >> 5) * 512 + ((d + 1) & 31) * 8] = f2bf(v1);
        vf_g[base0 + (size_t)((d + 2) >> 5) * 512 + ((d + 2) & 31) * 8] = f2bf(v2);
        vf_g[base0 + (size_t)((d + 3) >> 5) * 512 + ((d + 3) & 31) * 8] = f2bf(v3);
      }
    }
  }
}

// ---------------------------------------------------------------- proj GEMM
// 64(M) x 128(L) tile -> 512 blocks (2/CU) for HBM-write overlap.
__global__ __launch_bounds__(256) void gemm_proj(const u16* __restrict__ A_bf,
                                                 const u16* __restrict__ B_t,
                                                 const float* __restrict__ bias,
                                                 const float* __restrict__ xres,
                                                 float* __restrict__ out_f) {
  constexpr int K = 512;
  __shared__ u16 A_lds[64][32];
  __shared__ u16 B_lds[128][32];
  int t = threadIdx.x;
  int w = t >> 6, lane = t & 63;
  int q4 = lane >> 4, c15 = lane & 15;
  int o0 = blockIdx.y * 64;
  int l0 = blockIdx.x * 128;
  int b = blockIdx.z;
  const u16* Bb = B_t + (size_t)b * L_SEQ * K;
  f32x4 acc[4][2] = {};

  int sr = lane >> 2, sc = lane & 3;
  int ra = w * 16 + sr;
  int lca = (sc - (ra >> 1)) & 3;
  const u16* Ag = A_bf + (size_t)(o0 + ra) * K + lca * 8;
  int rb0 = w * 32 + sr, rb1 = rb0 + 16;
  int lcb0 = (sc - (rb0 >> 1)) & 3;
  int lcb1 = (sc - (rb1 >> 1)) & 3;
  const u16* Bg0 = Bb + (size_t)(l0 + rb0) * K + lcb0 * 8;
  const u16* Bg1 = Bb + (size_t)(l0 + rb1) * K + lcb1 * 8;
  u16* Al = &A_lds[w * 16][0];
  u16* Bl0 = &B_lds[w * 32][0];
  u16* Bl1 = &B_lds[w * 32 + 16][0];

  for (int kt = 0; kt < K / 32; ++kt) {
    gl16(Ag, Al);
    gl16(Bg0, Bl0); gl16(Bg1, Bl1);
    Ag += 32; Bg0 += 32; Bg1 += 32;
    __syncthreads();
    bf16x8 af[4], bfr[2];
#pragma unroll
    for (int mi = 0; mi < 4; ++mi) {
      int ar = mi * 16 + c15;
      af[mi] = *(const bf16x8*)&A_lds[ar][((q4 + (ar >> 1)) & 3) * 8];
    }
#pragma unroll
    for (int ni = 0; ni < 2; ++ni) {
      int br = w * 32 + ni * 16 + c15;
      bfr[ni] = *(const bf16x8*)&B_lds[br][((q4 + (br >> 1)) & 3) * 8];
    }
#pragma unroll
    for (int mi = 0; mi < 4; ++mi)
#pragma unroll
      for (int ni = 0; ni < 2; ++ni)
        acc[mi][ni] = __builtin_amdgcn_mfma_f32_16x16x32_bf16(af[mi], bfr[ni], acc[mi][ni], 0, 0, 0);
    __syncthreads();
  }

#pragma unroll
  for (int mi = 0; mi < 4; ++mi) {
    int orow = o0 + mi * 16 + q4 * 4;
    float4 bi = *(const float4*)&bias[orow];
#pragma unroll
    for (int ni = 0; ni < 2; ++ni) {
      int l = l0 + w * 32 + ni * 16 + c15;
      size_t base2 = ((size_t)(b * C_DIM + orow)) * L_SEQ + l;
      out_f[base2] = acc[mi][ni][0] + bi.x + xres[base2];
      out_f[base2 + L_SEQ] = acc[mi][ni][1] + bi.y + xres[base2 + L_SEQ];
      out_f[base2 + 2 * L_SEQ] = acc[mi][ni][2] + bi.z + xres[base2 + 2 * L_SEQ];
      out_f[base2 + 3 * L_SEQ] = acc[mi][ni][3] + bi.w + xres[base2 + 3 * L_SEQ];
    }
  }
}

// ---------------------------------------------------------------- attention
// QBLK=64 block: 4 waves = 2 q-groups x 2 KV-halves. NO-MAX softmax +
// S-pipeline (QK(t+1) before exp2(t)) + K AND V register double-buffers
// (V(t+2) loaded after PV(t) -> full-body latency cover). 2-way LDS merge.
#define ABODY(KL, KN, VC, SC, SN, T)                                           \
  {                                                                            \
    int tl = (T) + 2; tl = tl > 31 ? 31 : tl;                                  \
    const u16* kp = kfb + tl * 2048;                                           \
    const u16* vp = vfb + tl * 2048;                                           \
    KL[0] = *(const bf16x8*)(kp);                                              \
    KL[1] = *(const bf16x8*)(kp + 512);                                        \
    KL[2] = *(const bf16x8*)(kp + 1024);                                       \
    KL[3] = *(const bf16x8*)(kp + 1536);                                       \
    _Pragma("unroll") for (int r = 0; r < 16; ++r) SN[r] = 0.f;                \
    SN = __builtin_amdgcn_mfma_f32_32x32x16_bf16(KN[0], qf[0], SN, 0, 0, 0);   \
    SN = __builtin_amdgcn_mfma_f32_32x32x16_bf16(KN[1], qf[1], SN, 0, 0, 0);   \
    SN = __builtin_amdgcn_mfma_f32_32x32x16_bf16(KN[2], qf[2], SN, 0, 0, 0);   \
    SN = __builtin_amdgcn_mfma_f32_32x32x16_bf16(KN[3], qf[3], SN, 0, 0, 0);   \
    float e[16];                                                               \
    _Pragma("unroll") for (int r = 0; r < 16; ++r)                             \
        e[r] = __builtin_amdgcn_exp2f(SC[r]);                                  \
    f32x2 a0_ = {e[0], e[1]}, a1_ = {e[2], e[3]}, a2_ = {e[4], e[5]},          \
          a3_ = {e[6], e[7]}, a4_ = {e[8], e[9]}, a5_ = {e[10], e[11]},        \
          a6_ = {e[12], e[13]}, a7_ = {e[14], e[15]};                          \
    f32x2 b0_ = a0_ + a1_, b1_ = a2_ + a3_, b2_ = a4_ + a5_, b3_ = a6_ + a7_;  \
    f32x2 c0_ = b0_ + b1_, c1_ = b2_ + b3_;                                    \
    f32x2 d0_ = c0_ + c1_;                                                     \
    float sum = d0_[0] + d0_[1];                                               \
    sum += __shfl_xor(sum, 32);                                                \
    l_r += sum;                                                                \
    unsigned pk[8];                                                            \
    _Pragma("unroll") for (int i = 0; i < 8; ++i)                              \
        pk[i] = cvtpk_bf16(e[2 * i], e[2 * i + 1]);                            \
    pl32swap(pk[0], pk[2]); pl32swap(pk[1], pk[3]);                            \
    pl32swap(pk[4], pk[6]); pl32swap(pk[5], pk[7]);                            \
    bf16x8 pf0 = mk8(pk[0], pk[1], pk[2], pk[3]);                              \
    bf16x8 pf1 = mk8(pk[4], pk[5], pk[6], pk[7]);                              \
    o0 = __builtin_amdgcn_mfma_f32_32x32x16_bf16(VC[0], pf0, o0, 0, 0, 0);     \
    o1 = __builtin_amdgcn_mfma_f32_32x32x16_bf16(VC[1], pf0, o1, 0, 0, 0);     \
    o0 = __builtin_amdgcn_mfma_f32_32x32x16_bf16(VC[2], pf1, o0, 0, 0, 0);     \
    o1 = __builtin_amdgcn_mfma_f32_32x32x16_bf16(VC[3], pf1, o1, 0, 0, 0);     \
    VC[0] = *(const bf16x8*)(vp);                                              \
    VC[1] = *(const bf16x8*)(vp + 512);                                        \
    VC[2] = *(const bf16x8*)(vp + 1024);                                       \
    VC[3] = *(const bf16x8*)(vp + 1536);                                       \
  }

#define AEPI(VC, SC)                                                           \
  {                                                                            \
    float e[16];                                                               \
    _Pragma("unroll") for (int r = 0; r < 16; ++r)                             \
        e[r] = __builtin_amdgcn_exp2f(SC[r]);                                  \
    f32x2 a0_ = {e[0], e[1]}, a1_ = {e[2], e[3]}, a2_ = {e[4], e[5]},          \
          a3_ = {e[6], e[7]}, a4_ = {e[8], e[9]}, a5_ = {e[10], e[11]},        \
          a6_ = {e[12], e[13]}, a7_ = {e[14], e[15]};                          \
    f32x2 b0_ = a0_ + a1_, b1_ = a2_ + a3_, b2_ = a4_ + a5_, b3_ = a6_ + a7_;  \
    f32x2 c0_ = b0_ + b1_, c1_ = b2_ + b3_;                                    \
    f32x2 d0_ = c0_ + c1_;                                                     \
    float sum = d0_[0] + d0_[1];                                               \
    sum += __shfl_xor(sum, 32);                                                \
    l_r += sum;                                                                \
    unsigned pk[8];                                                            \
    _Pragma("unroll") for (int i = 0; i < 8; ++i)                              \
        pk[i] = cvtpk_bf16(e[2 * i], e[2 * i + 1]);                            \
    pl32swap(pk[0], pk[2]); pl32swap(pk[1], pk[3]);                            \
    pl32swap(pk[4], pk[6]); pl32swap(pk[5], pk[7]);                            \
    bf16x8 pf0 = mk8(pk[0], pk[1], pk[2], pk[3]);                              \
    bf16x8 pf1 = mk8(pk[4], pk[5], pk[6], pk[7]);                              \
    o0 = __builtin_amdgcn_mfma_f32_32x32x16_bf16(VC[0], pf0, o0, 0, 0, 0);     \
    o1 = __builtin_amdgcn_mfma_f32_32x32x16_bf16(VC[1], pf0, o1, 0, 0, 0);     \
    o0 = __builtin_amdgcn_mfma_f32_32x32x16_bf16(VC[2], pf1, o0, 0, 0, 0);     \
    o1 = __builtin_amdgcn_mfma_f32_32x32x16_bf16(VC[3], pf1, o1, 0, 0, 0);     \
  }

__global__ __launch_bounds__(256, 3) void attn_kernel(const u16* __restrict__ q_t,
                                                      const u16* __restrict__ kf_g,
                                                      const u16* __restrict__ vf_g,
                                                      u16* __restrict__ ao_t) {
  __shared__ float oL[4][64][32];
  __shared__ float lL[4][32];

  int g = blockIdx.x;
  int wk = (g & 7) * 128 + (g >> 3);  // XCD swizzle: 1024 wgs, 8 XCDs
  int qg = wk & 31, bh = wk >> 5;
  int b = bh >> 3, h = bh & 7;
  int t = threadIdx.x;
  int wv = t >> 6, lane = t & 63;
  int q = lane & 31, hi = lane >> 5;
  int qh = wv & 1, kvh = wv >> 1;
  int q0 = qg * 64 + qh * 32;

  const u16* qp = q_t + ((size_t)(b * L_SEQ + q0 + q)) * C_DIM + h * 64 + hi * 8;
  bf16x8 qf[4];
#pragma unroll
  for (int kk = 0; kk < 4; ++kk) qf[kk] = *(const bf16x8*)(qp + kk * 16);

  // wave's KV half: tiles [kvh*32, kvh*32+32)
  const u16* kfb = kf_g + (size_t)bh * 131072 + (size_t)kvh * 65536 + lane * 8;
  const u16* vfb = vf_g + (size_t)bh * 131072 + (size_t)kvh * 65536 + lane * 8;

  f32x16 o0, o1;
#pragma unroll
  for (int r = 0; r < 16; ++r) { o0[r] = 0.f; o1[r] = 0.f; }
  float l_r = 0.f;

  bf16x8 kA[4], kB[4], vA[4], vB[4];
#pragma unroll
  for (int i = 0; i < 4; ++i) {
    kB[i] = *(const bf16x8*)(kfb + i * 512);           // K(0)
    kA[i] = *(const bf16x8*)(kfb + 2048 + i * 512);    // K(1)
    vA[i] = *(const bf16x8*)(vfb + i * 512);           // V(0)
    vB[i] = *(const bf16x8*)(vfb + 2048 + i * 512);    // V(1)
  }
  f32x16 sA, sB;
#pragma unroll
  for (int r = 0; r < 16; ++r) sA[r] = 0.f;
#pragma unroll
  for (int kk = 0; kk < 4; ++kk)
    sA = __builtin_amdgcn_mfma_f32_32x32x16_bf16(kB[kk], qf[kk], sA, 0, 0, 0);  // S(0)

  for (int it = 0; it < 15; ++it) {
    ABODY(kB, kA, vA, sA, sB, 2 * it);
    ABODY(kA, kB, vB, sB, sA, 2 * it + 1);
  }
  ABODY(kB, kA, vA, sA, sB, 30);
  AEPI(vB, sB);

  // ---- merge 2 KV-halves per q-group via LDS (pure sums) ----
  if (hi == 0) lL[wv][q] = l_r;
#pragma unroll
  for (int r = 0; r < 16; ++r) {
    int d = (r & 3) + 8 * (r >> 2) + 4 * hi;
    oL[wv][d][q] = o0[r];
    oL[wv][d + 32][q] = o1[r];
  }
  __syncthreads();

  int tq = t & 31;
  int oqh = (t >> 5) & 1;
  int d0 = (t >> 6) * 16;
  float lsum = lL[oqh][tq] + lL[oqh + 2][tq];
  float inv = 1.f / lsum;
  float v[16];
#pragma unroll
  for (int i = 0; i < 16; ++i)
    v[i] = (oL[oqh][d0 + i][tq] + oL[oqh + 2][d0 + i][tq]) * inv;
  u16* dst = ao_t + ((size_t)(b * L_SEQ + qg * 64 + oqh * 32 + tq)) * C_DIM + h * 64 + d0;
  uint4 ov0, ov1;
  ov0.x = cvtpk_bf16(v[0], v[1]);
  ov0.y = cvtpk_bf16(v[2], v[3]);
  ov0.z = cvtpk_bf16(v[4], v[5]);
  ov0.w = cvtpk_bf16(v[6], v[7]);
  ov1.x = cvtpk_bf16(v[8], v[9]);
  ov1.y = cvtpk_bf16(v[10], v[11]);
  ov1.z = cvtpk_bf16(v[12], v[13]);
  ov1.w = cvtpk_bf16(v[14], v[15]);
  *(uint4*)dst = ov0;
  *(uint4*)(dst + 8) = ov1;
}

// ---------------------------------------------------------------- launch
extern "C" void kernel_launch(void* const* d_in, const int* in_sizes, int n_in,
                              void* d_out, int out_size, void* d_ws, size_t ws_size,
                              hipStream_t stream) {
  const float* x = (const float*)d_in[0];
  const float* gamma = (const float*)d_in[1];
  const float* beta = (const float*)d_in[2];
  const float* w_qkv = (const float*)d_in[3];
  const float* b_qkv = (const float*)d_in[4];
  const float* w_proj = (const float*)d_in[5];
  const float* b_proj = (const float*)d_in[6];
  float* out = (float*)d_out;

  u16* wq_bf = (u16*)d_ws;                 // 786432
  u16* wp_bf = wq_bf + 786432;             // 262144
  u16* h_t = wp_bf + 262144;               // 4194304 (b,l,c)
  u16* q_t = h_t + 4194304;                // (b,l,c), pre-scaled
  u16* kf_g = q_t + 4194304;               // K fragments
  u16* vf_g = kf_g + 4194304;              // V fragments
  u16* ao_t = vf_g + 4194304;              // (b,l,c)

  prep_kernel<<<dim3(1152), dim3(256), 0, stream>>>(x, gamma, beta, w_qkv, w_proj,
                                                    h_t, wq_bf, wp_bf);
  gemm_qkv<<<dim3(16, 12, 4), dim3(256), 0, stream>>>(wq_bf, h_t, b_qkv, q_t, kf_g, vf_g);
  attn_kernel<<<dim3(1024), dim3(256), 0, stream>>>(q_t, kf_g, vf_g, ao_t);
  gemm_proj<<<dim3(16, 8, 4), dim3(256), 0, stream>>>(wp_bf, ao_t, b_proj, x, out);
}